// Round 7
// baseline (235.288 us; speedup 1.0000x reference)
//
#include <hip/hip_runtime.h>

#define N_NODES 100000
#define N_EDGES 1600000
#define NFEAT 128
#define NHID 64

#define BBITS 7                                  // bucket = row >> 7 (128 rows)
#define NBUCK 782                                // ceil(100000 / 128)
#define BATCH 2048                               // edges per bin block
#define NBATCH ((N_EDGES + BATCH - 1) / BATCH)   // 782
#define STRIDE 2432                              // slot size per bucket (mean 2048 + 8.5 sigma)
#define CMASK 0x1FFFF                            // 17 bits for col

typedef __attribute__((ext_vector_type(8))) short short8;
typedef __attribute__((ext_vector_type(4))) float f32x4;

// fp32 -> bf16 round-to-nearest-even
__device__ __forceinline__ unsigned short f2bf(float f) {
  unsigned u = __float_as_uint(f);
  u += 0x7fffu + ((u >> 16) & 1u);
  return (unsigned short)(u >> 16);
}

// ---------------- Wt: W[k][n] -> Wt[n][k] bf16 + cursor init ----------------
__global__ __launch_bounds__(256) void gcn_wt(const float* __restrict__ W,
                                              unsigned short* __restrict__ wt,
                                              int* __restrict__ cursor) {
  const int i = blockIdx.x * 256 + threadIdx.x;   // 32 x 256 = 8192
  const int n = i >> 7;
  const int k = i & 127;
  wt[i] = f2bf(W[k * NHID + n]);
  if (blockIdx.x == 0)
    for (int b = threadIdx.x; b < NBUCK; b += 256)
      cursor[b * 16] = b * STRIDE;                // line-padded cursors
}

// ---------------- GEMM: support = x @ W via MFMA bf16 ----------------
__global__ __launch_bounds__(256) void gcn_gemm(const float* __restrict__ x,
                                                const unsigned short* __restrict__ wt,
                                                unsigned short* __restrict__ support_h) {
  __shared__ float ldsx[64 * NFEAT];  // 32 KB
  const int t = threadIdx.x;
  const int node0 = blockIdx.x * 64;
  const float4* __restrict__ gx = (const float4*)(x + (size_t)node0 * NFEAT);
  float4* lx4 = (float4*)ldsx;
  const int limit4 = (N_NODES - node0) * (NFEAT / 4);
#pragma unroll
  for (int i = 0; i < 8; ++i) {
    const int idx = i * 256 + t;
    if (idx < limit4) lx4[idx] = gx[idx];
  }
  __syncthreads();
  const int wv = t >> 6;
  const int lane = t & 63;
  const int quad = lane >> 4;
  const int nl = lane & 15;
  const int mrow = wv * 16 + nl;
  f32x4 acc[4];
#pragma unroll
  for (int nt = 0; nt < 4; ++nt)
#pragma unroll
    for (int r = 0; r < 4; ++r) acc[nt][r] = 0.f;
#pragma unroll
  for (int kc = 0; kc < 4; ++kc) {
    const float* ap = &ldsx[mrow * NFEAT + kc * 32 + quad * 8];
    const float4 a0 = *(const float4*)ap;
    const float4 a1 = *(const float4*)(ap + 4);
    union { short8 v; unsigned short s[8]; } au;
    au.s[0] = f2bf(a0.x); au.s[1] = f2bf(a0.y);
    au.s[2] = f2bf(a0.z); au.s[3] = f2bf(a0.w);
    au.s[4] = f2bf(a1.x); au.s[5] = f2bf(a1.y);
    au.s[6] = f2bf(a1.z); au.s[7] = f2bf(a1.w);
#pragma unroll
    for (int nt = 0; nt < 4; ++nt) {
      const short8 bf = *(const short8*)(wt + (size_t)(nt * 16 + nl) * NFEAT +
                                         kc * 32 + quad * 8);
      acc[nt] = __builtin_amdgcn_mfma_f32_16x16x32_bf16(au.v, bf, acc[nt], 0, 0, 0);
    }
  }
#pragma unroll
  for (int nt = 0; nt < 4; ++nt)
#pragma unroll
    for (int r = 0; r < 4; ++r) {
      const int node = node0 + wv * 16 + quad * 4 + r;
      if (node < N_NODES)
        support_h[(size_t)node * NHID + nt * 16 + nl] = f2bf(acc[nt][r]);
    }
}

// ---------------- binA: bucket-bin edges, slice grab via padded cursors -------
// eg[i] = { (r&127)<<17 | c , float_bits(val) }
__global__ __launch_bounds__(512) void gcn_bin(const int* __restrict__ erow,
                                               const int* __restrict__ ecol,
                                               const float* __restrict__ eval_,
                                               int* __restrict__ cursor,
                                               int2* __restrict__ eg) {
  __shared__ int h[NBUCK];       // counts, then dest_base
  __shared__ int ofs[NBUCK];
  __shared__ int sm[512];
  __shared__ int spx[BATCH];
  __shared__ int sv[BATCH];
  __shared__ short sb[BATCH];
  const int t = threadIdx.x;
  for (int i = t; i < NBUCK; i += 512) h[i] = 0;
  __syncthreads();
  const int base = blockIdx.x * BATCH;
  const int n = min(BATCH, N_EDGES - base);
  int mypx[4], myv[4], myrank[4], myb[4];
#pragma unroll
  for (int u = 0; u < 4; ++u) {
    const int j = t + u * 512;
    if (j < n) {
      const int r = erow[base + j];
      mypx[u] = ((r & 127) << 17) | ecol[base + j];
      myv[u] = __float_as_int(eval_[base + j]);
      myb[u] = r >> BBITS;
      myrank[u] = atomicAdd(&h[myb[u]], 1);
    }
  }
  __syncthreads();
  // 2-elem-per-thread exclusive scan of h[0..NBUCK) -> ofs
  const int k0 = 2 * t, k1 = 2 * t + 1;
  const int a0 = (k0 < NBUCK) ? h[k0] : 0;
  const int a1 = (k1 < NBUCK) ? h[k1] : 0;
  const int lsum = a0 + a1;
  sm[t] = lsum;
  __syncthreads();
  for (int off = 1; off < 512; off <<= 1) {
    const int xv = (t >= off) ? sm[t - off] : 0;
    __syncthreads();
    sm[t] += xv;
    __syncthreads();
  }
  const int excl = sm[t] - lsum;
  if (k0 < NBUCK) ofs[k0] = excl;
  if (k1 < NBUCK) ofs[k1] = excl + a0;
  __syncthreads();
  // stage sorted by bucket; grab global slices; h becomes dest_base
#pragma unroll
  for (int u = 0; u < 4; ++u) {
    const int j = t + u * 512;
    if (j < n) {
      const int pos = ofs[myb[u]] + myrank[u];
      spx[pos] = mypx[u];
      sv[pos] = myv[u];
      sb[pos] = (short)myb[u];
    }
  }
  for (int i = t; i < NBUCK; i += 512) {
    const int c = h[i];
    if (c > 0) {
      const int gb = atomicAdd(&cursor[i * 16], c);  // absolute elem index
      h[i] = gb - ofs[i];
    }
  }
  __syncthreads();
  for (int j = t; j < n; j += 512) {
    const int d = h[sb[j]] + j;   // consecutive j in same bucket -> consecutive d
    eg[d] = make_int2(spx[j], sv[j]);
  }
}

// ---------------- rowsort: stream counting-sort by row, eg -> eg2 -------------
// One block per bucket (782). Emits rs_re[node] = (start, end) into eg2.
__global__ __launch_bounds__(512) void gcn_rowsort(const int* __restrict__ cursor,
                                                   const int2* __restrict__ eg,
                                                   int2* __restrict__ eg2,
                                                   int2* __restrict__ rs_re) {
  __shared__ int cnt[128];
  __shared__ int sm[128];
  __shared__ int cur[128];
  const int t = threadIdx.x;
  const int k = blockIdx.x;
  const int bbase = k * STRIDE;
  const int n = cursor[k * 16] - bbase;
  if (t < 128) cnt[t] = 0;
  __syncthreads();
  // phase 1: count rows (keys only)
  const int* egx = (const int*)eg;
  for (int j = t; j < n; j += 512)
    atomicAdd(&cnt[((unsigned)egx[(size_t)(bbase + j) * 2]) >> 17], 1);
  __syncthreads();
  // exclusive scan of cnt[128]
  const int myc = (t < 128) ? cnt[t] : 0;
  if (t < 128) sm[t] = myc;
  __syncthreads();
  for (int off = 1; off < 128; off <<= 1) {
    int xv = 0;
    if (t >= off && t < 128) xv = sm[t - off];
    __syncthreads();
    if (t < 128) sm[t] += xv;
    __syncthreads();
  }
  if (t < 128) {
    const int start = bbase + sm[t] - myc;
    cur[t] = start;
    const int node = (k << BBITS) + t;
    if (node < N_NODES) rs_re[node] = make_int2(start, start + myc);
  }
  __syncthreads();
  // phase 2: stream scatter to final row-sorted position
  for (int j = t; j < n; j += 512) {
    const int2 p = eg[bbase + j];
    const int row = ((unsigned)p.x) >> 17;
    const int d = atomicAdd(&cur[row], 1);
    eg2[d] = make_int2(p.x & CMASK, p.y);
  }
}

// ---------------- Threefry-2x32 (JAX partitionable), key (0,42) ----------------
__device__ __forceinline__ unsigned rotl32(unsigned v, int r) {
  return (v << r) | (v >> (32 - r));
}

__device__ __forceinline__ unsigned threefry_draw(unsigned i) {
  const unsigned ks0 = 0u;
  const unsigned ks1 = 42u;
  const unsigned ks2 = 0x1BD11BDAu ^ 42u;
  unsigned x0 = 0u + ks0;
  unsigned x1 = i + ks1;
#define TF_ROUND(r) { x0 += x1; x1 = rotl32(x1, (r)); x1 ^= x0; }
  TF_ROUND(13) TF_ROUND(15) TF_ROUND(26) TF_ROUND(6)
  x0 += ks1; x1 += ks2 + 1u;
  TF_ROUND(17) TF_ROUND(29) TF_ROUND(16) TF_ROUND(24)
  x0 += ks2; x1 += ks0 + 2u;
  TF_ROUND(13) TF_ROUND(15) TF_ROUND(26) TF_ROUND(6)
  x0 += ks0; x1 += ks1 + 3u;
  TF_ROUND(17) TF_ROUND(29) TF_ROUND(16) TF_ROUND(24)
  x0 += ks1; x1 += ks2 + 4u;
  TF_ROUND(13) TF_ROUND(15) TF_ROUND(26) TF_ROUND(6)
  x0 += ks2; x1 += ks0 + 5u;
#undef TF_ROUND
  return x0 ^ x1;
}

// ---------------- aggregate (wave/node, 8 edges, butterfly reduce-scatter) ----
__global__ __launch_bounds__(256) void gcn_aggregate(const int2* __restrict__ rs_re,
                                                     const int2* __restrict__ eg2,
                                                     const unsigned short* __restrict__ support_h,
                                                     const float* __restrict__ b,
                                                     float* __restrict__ out) {
  const int node = (int)((blockIdx.x * 256u + threadIdx.x) >> 6);
  const int lane = threadIdx.x & 63;
  const int grp = lane >> 3;     // edge slot 0..7
  const int sub = lane & 7;      // 8 bf16 feats each (16 B)
  const int2 se = rs_re[node];
  const int s = se.x;
  const int e = se.y;
  float acc[8];
#pragma unroll
  for (int j = 0; j < 8; ++j) acc[j] = 0.f;
  for (int i = s; i < e; i += 8) {
    const int idx = i + grp;
    const int2 p = (idx < e) ? eg2[idx] : make_int2(0, 0);  // val 0 pad -> no-op
    const uint4 q = ((const uint4*)support_h)[(size_t)p.x * 8 + sub];
    const float v = __int_as_float(p.y);
    acc[0] = __builtin_fmaf(v, __uint_as_float(q.x << 16), acc[0]);
    acc[1] = __builtin_fmaf(v, __uint_as_float(q.x & 0xffff0000u), acc[1]);
    acc[2] = __builtin_fmaf(v, __uint_as_float(q.y << 16), acc[2]);
    acc[3] = __builtin_fmaf(v, __uint_as_float(q.y & 0xffff0000u), acc[3]);
    acc[4] = __builtin_fmaf(v, __uint_as_float(q.z << 16), acc[4]);
    acc[5] = __builtin_fmaf(v, __uint_as_float(q.z & 0xffff0000u), acc[5]);
    acc[6] = __builtin_fmaf(v, __uint_as_float(q.w << 16), acc[6]);
    acc[7] = __builtin_fmaf(v, __uint_as_float(q.w & 0xffff0000u), acc[7]);
  }
  // Butterfly reduce-scatter over grp bits, keeping j = grp.
  const int g0 = grp & 1, g1 = (grp >> 1) & 1, g2 = grp >> 2;
  float v4[4];
#pragma unroll
  for (int i = 0; i < 4; ++i) {
    const float keep = g0 ? acc[2 * i + 1] : acc[2 * i];
    const float give = g0 ? acc[2 * i] : acc[2 * i + 1];
    v4[i] = keep + __shfl_xor(give, 8);
  }
  float v2[2];
#pragma unroll
  for (int i = 0; i < 2; ++i) {
    const float keep = g1 ? v4[2 * i + 1] : v4[2 * i];
    const float give = g1 ? v4[2 * i] : v4[2 * i + 1];
    v2[i] = keep + __shfl_xor(give, 16);
  }
  const float keep = g2 ? v2[1] : v2[0];
  const float give = g2 ? v2[0] : v2[1];
  const float aval = keep + __shfl_xor(give, 32);
  const int feat = (sub << 3) | grp;
  const float h = fmaxf(aval + b[feat], 0.f);
  const unsigned idxg = (unsigned)node * 64u + (unsigned)feat;
  const bool keepm = (threefry_draw(idxg) >> 31) == 0u;
  out[idxg] = keepm ? h * 2.0f : 0.0f;
}

extern "C" void kernel_launch(void* const* d_in, const int* in_sizes, int n_in,
                              void* d_out, int out_size, void* d_ws, size_t ws_size,
                              hipStream_t stream) {
  const float* x     = (const float*)d_in[0];
  const int*   erow  = (const int*)d_in[1];
  const int*   ecol  = (const int*)d_in[2];
  const float* eval_ = (const float*)d_in[3];
  const float* W     = (const float*)d_in[4];
  const float* b     = (const float*)d_in[5];
  float* out = (float*)d_out;

  // Workspace layout (bytes), total ~44.1 MB (<= 45.4 MB proven in R2):
  char* ws = (char*)d_ws;
  unsigned short* support_h = (unsigned short*)(ws);             // 12,800,000
  unsigned short* wt        = (unsigned short*)(ws + 12800000);  //     16,384
  int2* rs_re   = (int2*)(ws + 12816384);                        //    800,000
  int*  cursor  = (int*)(ws + 13616384);                         //     50,048 (782 x 64B)
  int2* eg      = (int2*)(ws + 13666432);                        // 15,214,592 (782 x 2432 x 8)
  int2* eg2     = (int2*)(ws + 28881024);                        // 15,214,592

  hipLaunchKernelGGL(gcn_wt, dim3(32), dim3(256), 0, stream, W, wt, cursor);
  hipLaunchKernelGGL(gcn_gemm, dim3((N_NODES + 63) / 64), dim3(256), 0, stream,
                     x, wt, support_h);
  hipLaunchKernelGGL(gcn_bin, dim3(NBATCH), dim3(512), 0, stream,
                     erow, ecol, eval_, cursor, eg);
  hipLaunchKernelGGL(gcn_rowsort, dim3(NBUCK), dim3(512), 0, stream,
                     cursor, eg, eg2, rs_re);
  hipLaunchKernelGGL(gcn_aggregate, dim3(N_NODES / 4), dim3(256), 0, stream,
                     rs_re, eg2, support_h, b, out);
}

// Round 8
// 207.819 us; speedup vs baseline: 1.1322x; 1.1322x over previous
//
#include <hip/hip_runtime.h>

#define N_NODES 100000
#define N_EDGES 1600000
#define NFEAT 128
#define NHID 64

#define BBITS 8                                  // bucket = row >> 8 (256 rows)
#define NBUCK 391                                // ceil(100000 / 256)
#define BATCH 4096                               // edges per bin block
#define NBATCH ((N_EDGES + BATCH - 1) / BATCH)   // 391
#define STRIDE 4608                              // bucket slot size (mean 4092 + 8 sigma)
#define CMASK 0x1FFFF                            // 17 bits for col

typedef __attribute__((ext_vector_type(8))) short short8;
typedef __attribute__((ext_vector_type(4))) float f32x4;

// fp32 -> bf16 round-to-nearest-even
__device__ __forceinline__ unsigned short f2bf(float f) {
  unsigned u = __float_as_uint(f);
  u += 0x7fffu + ((u >> 16) & 1u);
  return (unsigned short)(u >> 16);
}

// ---------------- Wt: W[k][n] -> Wt[n][k] bf16 + cursor init ----------------
__global__ __launch_bounds__(256) void gcn_wt(const float* __restrict__ W,
                                              unsigned short* __restrict__ wt,
                                              int* __restrict__ cursor) {
  const int i = blockIdx.x * 256 + threadIdx.x;   // 32 x 256 = 8192
  const int n = i >> 7;
  const int k = i & 127;
  wt[i] = f2bf(W[k * NHID + n]);
  if (blockIdx.x == 0)
    for (int b = threadIdx.x; b < NBUCK; b += 256)
      cursor[b * 16] = b * STRIDE;                // line-padded cursors
}

// ---------------- GEMM: support = x @ W via MFMA bf16 ----------------
__global__ __launch_bounds__(256) void gcn_gemm(const float* __restrict__ x,
                                                const unsigned short* __restrict__ wt,
                                                unsigned short* __restrict__ support_h) {
  __shared__ float ldsx[64 * NFEAT];  // 32 KB
  const int t = threadIdx.x;
  const int node0 = blockIdx.x * 64;
  const float4* __restrict__ gx = (const float4*)(x + (size_t)node0 * NFEAT);
  float4* lx4 = (float4*)ldsx;
  const int limit4 = (N_NODES - node0) * (NFEAT / 4);
#pragma unroll
  for (int i = 0; i < 8; ++i) {
    const int idx = i * 256 + t;
    if (idx < limit4) lx4[idx] = gx[idx];
  }
  __syncthreads();
  const int wv = t >> 6;
  const int lane = t & 63;
  const int quad = lane >> 4;
  const int nl = lane & 15;
  const int mrow = wv * 16 + nl;
  f32x4 acc[4];
#pragma unroll
  for (int nt = 0; nt < 4; ++nt)
#pragma unroll
    for (int r = 0; r < 4; ++r) acc[nt][r] = 0.f;
#pragma unroll
  for (int kc = 0; kc < 4; ++kc) {
    const float* ap = &ldsx[mrow * NFEAT + kc * 32 + quad * 8];
    const float4 a0 = *(const float4*)ap;
    const float4 a1 = *(const float4*)(ap + 4);
    union { short8 v; unsigned short s[8]; } au;
    au.s[0] = f2bf(a0.x); au.s[1] = f2bf(a0.y);
    au.s[2] = f2bf(a0.z); au.s[3] = f2bf(a0.w);
    au.s[4] = f2bf(a1.x); au.s[5] = f2bf(a1.y);
    au.s[6] = f2bf(a1.z); au.s[7] = f2bf(a1.w);
#pragma unroll
    for (int nt = 0; nt < 4; ++nt) {
      const short8 bf = *(const short8*)(wt + (size_t)(nt * 16 + nl) * NFEAT +
                                         kc * 32 + quad * 8);
      acc[nt] = __builtin_amdgcn_mfma_f32_16x16x32_bf16(au.v, bf, acc[nt], 0, 0, 0);
    }
  }
#pragma unroll
  for (int nt = 0; nt < 4; ++nt)
#pragma unroll
    for (int r = 0; r < 4; ++r) {
      const int node = node0 + wv * 16 + quad * 4 + r;
      if (node < N_NODES)
        support_h[(size_t)node * NHID + nt * 16 + nl] = f2bf(acc[nt][r]);
    }
}

// ---------------- bin: bucket-bin edges, slice grab via padded cursors --------
// eg[i] = { (r&255)<<17 | c , float_bits(val) }
__global__ __launch_bounds__(512) void gcn_bin(const int* __restrict__ erow,
                                               const int* __restrict__ ecol,
                                               const float* __restrict__ eval_,
                                               int* __restrict__ cursor,
                                               int2* __restrict__ eg) {
  __shared__ int h[NBUCK];       // counts, then dest_base
  __shared__ int ofs[NBUCK];
  __shared__ int sm[512];
  __shared__ int spx[BATCH];
  __shared__ int sv[BATCH];
  __shared__ short sb[BATCH];
  const int t = threadIdx.x;
  if (t < NBUCK) h[t] = 0;
  __syncthreads();
  const int base = blockIdx.x * BATCH;
  const int n = min(BATCH, N_EDGES - base);
  int mypx[8], myv[8], myrank[8], myb[8];
#pragma unroll
  for (int u = 0; u < 8; ++u) {
    const int j = t + u * 512;
    if (j < n) {
      const int r = erow[base + j];
      mypx[u] = ((r & 255) << 17) | ecol[base + j];
      myv[u] = __float_as_int(eval_[base + j]);
      myb[u] = r >> BBITS;
      myrank[u] = atomicAdd(&h[myb[u]], 1);
    }
  }
  __syncthreads();
  // exclusive scan of h[0..NBUCK) -> ofs
  const int hv = (t < NBUCK) ? h[t] : 0;
  sm[t] = hv;
  __syncthreads();
  for (int off = 1; off < 512; off <<= 1) {
    const int xv = (t >= off) ? sm[t - off] : 0;
    __syncthreads();
    sm[t] += xv;
    __syncthreads();
  }
  if (t < NBUCK) ofs[t] = sm[t] - hv;
  __syncthreads();
  // stage sorted by bucket
#pragma unroll
  for (int u = 0; u < 8; ++u) {
    const int j = t + u * 512;
    if (j < n) {
      const int pos = ofs[myb[u]] + myrank[u];
      spx[pos] = mypx[u];
      sv[pos] = myv[u];
      sb[pos] = (short)myb[u];
    }
  }
  // grab global slices; h becomes dest_base
  if (t < NBUCK) {
    const int c = h[t];
    if (c > 0) {
      const int gb = atomicAdd(&cursor[t * 16], c);  // absolute elem index
      h[t] = gb - ofs[t];
    }
  }
  __syncthreads();
  for (int j = t; j < n; j += 512) {
    const int d = h[sb[j]] + j;   // consecutive j in same bucket -> consecutive d
    eg[d] = make_int2(spx[j], sv[j]);
  }
}

// ---------------- rowsort: in-place counting sort by row within bucket --------
// One block per bucket. Register-staged (capacity 512*9 = 4608 = STRIDE).
// Emits rs_re[node] = (start, end).
__global__ __launch_bounds__(512) void gcn_rowsort(const int* __restrict__ cursor,
                                                   int2* __restrict__ eg,
                                                   int2* __restrict__ rs_re) {
  __shared__ int cnt[256];
  __shared__ int sm[256];
  __shared__ int rofs[256];
  const int t = threadIdx.x;
  const int k = blockIdx.x;
  const int bbase = k * STRIDE;
  const int n = cursor[k * 16] - bbase;
  if (t < 256) cnt[t] = 0;
  __syncthreads();
  int px[9], pv[9], rk[9];
#pragma unroll
  for (int u = 0; u < 9; ++u) {
    const int j = t + u * 512;
    if (j < n) {
      const int2 p = eg[bbase + j];
      px[u] = p.x;
      pv[u] = p.y;
      rk[u] = atomicAdd(&cnt[((unsigned)p.x) >> 17], 1);
    }
  }
  __syncthreads();
  const int myc = (t < 256) ? cnt[t] : 0;
  if (t < 256) sm[t] = myc;
  __syncthreads();
  for (int off = 1; off < 256; off <<= 1) {
    int xv = 0;
    if (t >= off && t < 256) xv = sm[t - off];
    __syncthreads();
    if (t < 256) sm[t] += xv;
    __syncthreads();
  }
  if (t < 256) {
    rofs[t] = sm[t] - myc;  // exclusive
    const int node = (k << BBITS) + t;
    const int start = bbase + sm[t] - myc;
    if (node < N_NODES) rs_re[node] = make_int2(start, start + myc);
  }
  __syncthreads();
#pragma unroll
  for (int u = 0; u < 9; ++u) {
    const int j = t + u * 512;
    if (j < n) {
      const int d = bbase + rofs[px[u] >> 17] + rk[u];
      eg[d] = make_int2(px[u] & CMASK, pv[u]);   // clean col
    }
  }
}

// ---------------- Threefry-2x32 (JAX partitionable), key (0,42) ----------------
__device__ __forceinline__ unsigned rotl32(unsigned v, int r) {
  return (v << r) | (v >> (32 - r));
}

__device__ __forceinline__ unsigned threefry_draw(unsigned i) {
  const unsigned ks0 = 0u;
  const unsigned ks1 = 42u;
  const unsigned ks2 = 0x1BD11BDAu ^ 42u;
  unsigned x0 = 0u + ks0;
  unsigned x1 = i + ks1;
#define TF_ROUND(r) { x0 += x1; x1 = rotl32(x1, (r)); x1 ^= x0; }
  TF_ROUND(13) TF_ROUND(15) TF_ROUND(26) TF_ROUND(6)
  x0 += ks1; x1 += ks2 + 1u;
  TF_ROUND(17) TF_ROUND(29) TF_ROUND(16) TF_ROUND(24)
  x0 += ks2; x1 += ks0 + 2u;
  TF_ROUND(13) TF_ROUND(15) TF_ROUND(26) TF_ROUND(6)
  x0 += ks0; x1 += ks1 + 3u;
  TF_ROUND(17) TF_ROUND(29) TF_ROUND(16) TF_ROUND(24)
  x0 += ks1; x1 += ks2 + 4u;
  TF_ROUND(13) TF_ROUND(15) TF_ROUND(26) TF_ROUND(6)
  x0 += ks2; x1 += ks0 + 5u;
#undef TF_ROUND
  return x0 ^ x1;
}

// ---------------- aggregate (wave/node, 8 edges, butterfly reduce-scatter) ----
__global__ __launch_bounds__(256) void gcn_aggregate(const int2* __restrict__ rs_re,
                                                     const int2* __restrict__ eg,
                                                     const unsigned short* __restrict__ support_h,
                                                     const float* __restrict__ b,
                                                     float* __restrict__ out) {
  const int node = (int)((blockIdx.x * 256u + threadIdx.x) >> 6);
  const int lane = threadIdx.x & 63;
  const int grp = lane >> 3;     // edge slot 0..7
  const int sub = lane & 7;      // 8 bf16 feats each (16 B)
  const int2 se = rs_re[node];
  const int s = se.x;
  const int e = se.y;
  float acc[8];
#pragma unroll
  for (int j = 0; j < 8; ++j) acc[j] = 0.f;
  for (int i = s; i < e; i += 8) {
    const int idx = i + grp;
    const int2 p = (idx < e) ? eg[idx] : make_int2(0, 0);  // val 0 pad -> no-op
    const uint4 q = ((const uint4*)support_h)[(size_t)p.x * 8 + sub];
    const float v = __int_as_float(p.y);
    acc[0] = __builtin_fmaf(v, __uint_as_float(q.x << 16), acc[0]);
    acc[1] = __builtin_fmaf(v, __uint_as_float(q.x & 0xffff0000u), acc[1]);
    acc[2] = __builtin_fmaf(v, __uint_as_float(q.y << 16), acc[2]);
    acc[3] = __builtin_fmaf(v, __uint_as_float(q.y & 0xffff0000u), acc[3]);
    acc[4] = __builtin_fmaf(v, __uint_as_float(q.z << 16), acc[4]);
    acc[5] = __builtin_fmaf(v, __uint_as_float(q.z & 0xffff0000u), acc[5]);
    acc[6] = __builtin_fmaf(v, __uint_as_float(q.w << 16), acc[6]);
    acc[7] = __builtin_fmaf(v, __uint_as_float(q.w & 0xffff0000u), acc[7]);
  }
  // Butterfly reduce-scatter over grp bits, keeping j = grp.
  const int g0 = grp & 1, g1 = (grp >> 1) & 1, g2 = grp >> 2;
  float v4[4];
#pragma unroll
  for (int i = 0; i < 4; ++i) {
    const float keep = g0 ? acc[2 * i + 1] : acc[2 * i];
    const float give = g0 ? acc[2 * i] : acc[2 * i + 1];
    v4[i] = keep + __shfl_xor(give, 8);
  }
  float v2[2];
#pragma unroll
  for (int i = 0; i < 2; ++i) {
    const float keep = g1 ? v4[2 * i + 1] : v4[2 * i];
    const float give = g1 ? v4[2 * i] : v4[2 * i + 1];
    v2[i] = keep + __shfl_xor(give, 16);
  }
  const float keep = g2 ? v2[1] : v2[0];
  const float give = g2 ? v2[0] : v2[1];
  const float aval = keep + __shfl_xor(give, 32);
  const int feat = (sub << 3) | grp;
  const float h = fmaxf(aval + b[feat], 0.f);
  const unsigned idxg = (unsigned)node * 64u + (unsigned)feat;
  const bool keepm = (threefry_draw(idxg) >> 31) == 0u;
  out[idxg] = keepm ? h * 2.0f : 0.0f;
}

extern "C" void kernel_launch(void* const* d_in, const int* in_sizes, int n_in,
                              void* d_out, int out_size, void* d_ws, size_t ws_size,
                              hipStream_t stream) {
  const float* x     = (const float*)d_in[0];
  const int*   erow  = (const int*)d_in[1];
  const int*   ecol  = (const int*)d_in[2];
  const float* eval_ = (const float*)d_in[3];
  const float* W     = (const float*)d_in[4];
  const float* b     = (const float*)d_in[5];
  float* out = (float*)d_out;

  // Workspace layout (bytes), total ~28.1 MB:
  char* ws = (char*)d_ws;
  unsigned short* support_h = (unsigned short*)(ws);             // 12,800,000
  unsigned short* wt        = (unsigned short*)(ws + 12800000);  //     16,384
  int2* rs_re   = (int2*)(ws + 12816384);                        //    800,000
  int*  cursor  = (int*)(ws + 13616384);                         //     25,088 (391 x 64B)
  int2* eg      = (int2*)(ws + 13641472);                        // 14,413,824 (391 x 4608 x 8)

  hipLaunchKernelGGL(gcn_wt, dim3(32), dim3(256), 0, stream, W, wt, cursor);
  hipLaunchKernelGGL(gcn_gemm, dim3((N_NODES + 63) / 64), dim3(256), 0, stream,
                     x, wt, support_h);
  hipLaunchKernelGGL(gcn_bin, dim3(NBATCH), dim3(512), 0, stream,
                     erow, ecol, eval_, cursor, eg);
  hipLaunchKernelGGL(gcn_rowsort, dim3(NBUCK), dim3(512), 0, stream,
                     cursor, eg, rs_re);
  hipLaunchKernelGGL(gcn_aggregate, dim3(N_NODES / 4), dim3(256), 0, stream,
                     rs_re, eg, support_h, b, out);
}

// Round 9
// 194.035 us; speedup vs baseline: 1.2126x; 1.0710x over previous
//
#include <hip/hip_runtime.h>

#define N_NODES 100000
#define N_EDGES 1600000
#define NFEAT 128
#define NHID 64

#define BBITS 8                                  // bucket = row >> 8 (256 rows)
#define NBUCK 391                                // ceil(100000 / 256)
#define BATCH 4096                               // edges per bin block
#define NBATCH ((N_EDGES + BATCH - 1) / BATCH)   // 391
#define NREP 4                                   // cursor replicas per bucket
#define RSTRIDE 1536                             // records per replica span (mean 1024 + 16 sigma)
#define HCAP 2560                                // LDS staging cap per half-bucket (mean 2048 + 11 sigma)
#define CMASK 0x1FFFF                            // 17 bits for col

typedef __attribute__((ext_vector_type(8))) short short8;
typedef __attribute__((ext_vector_type(4))) float f32x4;

// fp32 -> bf16 round-to-nearest-even
__device__ __forceinline__ unsigned short f2bf(float f) {
  unsigned u = __float_as_uint(f);
  u += 0x7fffu + ((u >> 16) & 1u);
  return (unsigned short)(u >> 16);
}

// ---------------- Wt: W[k][n] -> Wt[n][k] bf16 + cursor init ----------------
__global__ __launch_bounds__(256) void gcn_wt(const float* __restrict__ W,
                                              unsigned short* __restrict__ wt,
                                              int* __restrict__ cursor) {
  const int i = blockIdx.x * 256 + threadIdx.x;   // 32 x 256 = 8192
  const int n = i >> 7;
  const int k = i & 127;
  wt[i] = f2bf(W[k * NHID + n]);
  if (blockIdx.x == 0)
    for (int b = threadIdx.x; b < NBUCK * NREP; b += 256)
      cursor[b * 16] = 0;                         // line-padded counters
}

// ---------------- GEMM: support = x @ W via MFMA bf16 ----------------
__global__ __launch_bounds__(256) void gcn_gemm(const float* __restrict__ x,
                                                const unsigned short* __restrict__ wt,
                                                unsigned short* __restrict__ support_h) {
  __shared__ float ldsx[64 * NFEAT];  // 32 KB
  const int t = threadIdx.x;
  const int node0 = blockIdx.x * 64;
  const float4* __restrict__ gx = (const float4*)(x + (size_t)node0 * NFEAT);
  float4* lx4 = (float4*)ldsx;
  const int limit4 = (N_NODES - node0) * (NFEAT / 4);
#pragma unroll
  for (int i = 0; i < 8; ++i) {
    const int idx = i * 256 + t;
    if (idx < limit4) lx4[idx] = gx[idx];
  }
  __syncthreads();
  const int wv = t >> 6;
  const int lane = t & 63;
  const int quad = lane >> 4;
  const int nl = lane & 15;
  const int mrow = wv * 16 + nl;
  f32x4 acc[4];
#pragma unroll
  for (int nt = 0; nt < 4; ++nt)
#pragma unroll
    for (int r = 0; r < 4; ++r) acc[nt][r] = 0.f;
#pragma unroll
  for (int kc = 0; kc < 4; ++kc) {
    const float* ap = &ldsx[mrow * NFEAT + kc * 32 + quad * 8];
    const float4 a0 = *(const float4*)ap;
    const float4 a1 = *(const float4*)(ap + 4);
    union { short8 v; unsigned short s[8]; } au;
    au.s[0] = f2bf(a0.x); au.s[1] = f2bf(a0.y);
    au.s[2] = f2bf(a0.z); au.s[3] = f2bf(a0.w);
    au.s[4] = f2bf(a1.x); au.s[5] = f2bf(a1.y);
    au.s[6] = f2bf(a1.z); au.s[7] = f2bf(a1.w);
#pragma unroll
    for (int nt = 0; nt < 4; ++nt) {
      const short8 bf = *(const short8*)(wt + (size_t)(nt * 16 + nl) * NFEAT +
                                         kc * 32 + quad * 8);
      acc[nt] = __builtin_amdgcn_mfma_f32_16x16x32_bf16(au.v, bf, acc[nt], 0, 0, 0);
    }
  }
#pragma unroll
  for (int nt = 0; nt < 4; ++nt)
#pragma unroll
    for (int r = 0; r < 4; ++r) {
      const int node = node0 + wv * 16 + quad * 4 + r;
      if (node < N_NODES)
        support_h[(size_t)node * NHID + nt * 16 + nl] = f2bf(acc[nt][r]);
    }
}

// ---------------- bin: bucket-bin edges into replica spans --------------------
// eg[i] = { (r&255)<<17 | c , float_bits(val) }. Span s = bucket*NREP + rep.
__global__ __launch_bounds__(512) void gcn_bin(const int* __restrict__ erow,
                                               const int* __restrict__ ecol,
                                               const float* __restrict__ eval_,
                                               int* __restrict__ cursor,
                                               int2* __restrict__ eg) {
  __shared__ int h[NBUCK];       // counts, then dest_base
  __shared__ int ofs[NBUCK];
  __shared__ int wsum[8];
  __shared__ int spx[BATCH];
  __shared__ int sv[BATCH];
  __shared__ short sb[BATCH];
  const int t = threadIdx.x;
  const int rep = blockIdx.x & (NREP - 1);
  if (t < NBUCK) h[t] = 0;
  __syncthreads();
  const int base = blockIdx.x * BATCH;
  const int n = min(BATCH, N_EDGES - base);
  int mypx[8], myv[8], myrank[8], myb[8];
#pragma unroll
  for (int u = 0; u < 8; ++u) {
    const int j = t + u * 512;
    if (j < n) {
      const int r = erow[base + j];
      mypx[u] = ((r & 255) << 17) | ecol[base + j];
      myv[u] = __float_as_int(eval_[base + j]);
      myb[u] = r >> BBITS;
      myrank[u] = atomicAdd(&h[myb[u]], 1);
    }
  }
  __syncthreads();
  // wave-shfl exclusive scan of h[0..NBUCK) -> ofs (2 barriers)
  const int hv = (t < NBUCK) ? h[t] : 0;
  const int lane = t & 63;
  int v = hv;
#pragma unroll
  for (int off = 1; off < 64; off <<= 1) {
    const int u = __shfl_up(v, off);
    if (lane >= off) v += u;
  }
  if (lane == 63) wsum[t >> 6] = v;
  __syncthreads();
  int wbase = 0;
  const int mywv = t >> 6;
  for (int w = 0; w < mywv; ++w) wbase += wsum[w];
  const int my_ofs = wbase + v - hv;  // exclusive
  if (t < NBUCK) {
    ofs[t] = my_ofs;
    // grab replica span slice early (overlaps staging below)
    const int c = hv;
    if (c > 0) {
      const int old = atomicAdd(&cursor[(t * NREP + rep) * 16], c);
      h[t] = (t * NREP + rep) * RSTRIDE + old - my_ofs;  // dest_base - local_ofs
    }
  }
  __syncthreads();
  // stage sorted by bucket
#pragma unroll
  for (int u = 0; u < 8; ++u) {
    const int j = t + u * 512;
    if (j < n) {
      const int pos = ofs[myb[u]] + myrank[u];
      spx[pos] = mypx[u];
      sv[pos] = myv[u];
      sb[pos] = (short)myb[u];
    }
  }
  __syncthreads();
  for (int j = t; j < n; j += 512) {
    const int d = h[sb[j]] + j;   // consecutive j in same bucket -> consecutive d
    eg[d] = make_int2(spx[j], sv[j]);
  }
}

// ---------------- Threefry-2x32 (JAX partitionable), key (0,42) ----------------
__device__ __forceinline__ unsigned rotl32(unsigned v, int r) {
  return (v << r) | (v >> (32 - r));
}

__device__ __forceinline__ unsigned threefry_draw(unsigned i) {
  const unsigned ks0 = 0u;
  const unsigned ks1 = 42u;
  const unsigned ks2 = 0x1BD11BDAu ^ 42u;
  unsigned x0 = 0u + ks0;
  unsigned x1 = i + ks1;
#define TF_ROUND(r) { x0 += x1; x1 = rotl32(x1, (r)); x1 ^= x0; }
  TF_ROUND(13) TF_ROUND(15) TF_ROUND(26) TF_ROUND(6)
  x0 += ks1; x1 += ks2 + 1u;
  TF_ROUND(17) TF_ROUND(29) TF_ROUND(16) TF_ROUND(24)
  x0 += ks2; x1 += ks0 + 2u;
  TF_ROUND(13) TF_ROUND(15) TF_ROUND(26) TF_ROUND(6)
  x0 += ks0; x1 += ks1 + 3u;
  TF_ROUND(17) TF_ROUND(29) TF_ROUND(16) TF_ROUND(24)
  x0 += ks1; x1 += ks2 + 4u;
  TF_ROUND(13) TF_ROUND(15) TF_ROUND(26) TF_ROUND(6)
  x0 += ks2; x1 += ks0 + 5u;
#undef TF_ROUND
  return x0 ^ x1;
}

// ---------------- rowagg: fused rowsort (to LDS) + aggregate ------------------
// Grid 2*NBUCK; block handles 128 rows (half = blockIdx&1) of bucket blockIdx>>1.
__global__ __launch_bounds__(512) void gcn_rowagg(const int* __restrict__ cursor,
                                                  const int2* __restrict__ eg,
                                                  const unsigned short* __restrict__ support_h,
                                                  const float* __restrict__ b,
                                                  float* __restrict__ out) {
  __shared__ int2 srec[HCAP];    // 20 KB row-sorted records
  __shared__ int cnt[128];
  __shared__ int rstart[128];
  const int t = threadIdx.x;
  const int k = blockIdx.x >> 1;
  const int half = blockIdx.x & 1;
  if (t < 128) cnt[t] = 0;
  __syncthreads();
  // phase 1: register-load the bucket's 4 replica spans, keep-filter, rank
  int px[12], pv[12], rk[12];
  int idx = 0;
#pragma unroll
  for (int rep = 0; rep < NREP; ++rep) {
    const int span = k * NREP + rep;
    const int n = cursor[span * 16];
    const int sbase = span * RSTRIDE;
#pragma unroll
    for (int u = 0; u < 3; ++u, ++idx) {
      const int j = t + u * 512;
      const bool ok = j < n;
      int2 p = make_int2(0, 0);
      if (ok) p = eg[sbase + j];
      px[idx] = p.x;
      pv[idx] = p.y;
      const int r = ((unsigned)p.x) >> 17;
      rk[idx] = (ok && ((r >> 7) == half)) ? atomicAdd(&cnt[r & 127], 1) : -1;
    }
  }
  __syncthreads();
  // wave-0 scan of cnt[128] -> rstart
  if (t < 64) {
    const int a0 = cnt[t];
    const int a1 = cnt[64 + t];
    int s0 = a0;
#pragma unroll
    for (int off = 1; off < 64; off <<= 1) {
      const int u = __shfl_up(s0, off);
      if (t >= off) s0 += u;
    }
    const int tot0 = __shfl(s0, 63);
    int s1 = a1;
#pragma unroll
    for (int off = 1; off < 64; off <<= 1) {
      const int u = __shfl_up(s1, off);
      if (t >= off) s1 += u;
    }
    rstart[t] = s0 - a0;
    rstart[64 + t] = tot0 + s1 - a1;
  }
  __syncthreads();
  // scatter kept records into LDS, sorted by row
#pragma unroll
  for (int u = 0; u < 12; ++u) {
    if (rk[u] >= 0) {
      const int r = (((unsigned)px[u]) >> 17) & 127;
      srec[rstart[r] + rk[u]] = make_int2(px[u] & CMASK, pv[u]);
    }
  }
  __syncthreads();
  // phase 2: aggregate 8 waves x 16 rows, 8 edges in flight, butterfly RS
  const int wv = t >> 6;
  const int lane = t & 63;
  const int grp = lane >> 3;
  const int sub = lane & 7;
  const int feat = (sub << 3) | grp;
  const float bias = b[feat];
  for (int rr = 0; rr < 16; ++rr) {
    const int r = wv * 16 + rr;
    const int node = (k << BBITS) + (half << 7) + r;
    if (node >= N_NODES) break;  // wave-uniform
    const int s = rstart[r];
    const int e = s + cnt[r];
    float acc[8];
#pragma unroll
    for (int j = 0; j < 8; ++j) acc[j] = 0.f;
    for (int i = s; i < e; i += 8) {
      const int ii = i + grp;
      int2 p = make_int2(0, 0);
      if (ii < e) p = srec[ii];
      const uint4 q = ((const uint4*)support_h)[(size_t)p.x * 8 + sub];
      const float v = __int_as_float(p.y);
      acc[0] = __builtin_fmaf(v, __uint_as_float(q.x << 16), acc[0]);
      acc[1] = __builtin_fmaf(v, __uint_as_float(q.x & 0xffff0000u), acc[1]);
      acc[2] = __builtin_fmaf(v, __uint_as_float(q.y << 16), acc[2]);
      acc[3] = __builtin_fmaf(v, __uint_as_float(q.y & 0xffff0000u), acc[3]);
      acc[4] = __builtin_fmaf(v, __uint_as_float(q.z << 16), acc[4]);
      acc[5] = __builtin_fmaf(v, __uint_as_float(q.z & 0xffff0000u), acc[5]);
      acc[6] = __builtin_fmaf(v, __uint_as_float(q.w << 16), acc[6]);
      acc[7] = __builtin_fmaf(v, __uint_as_float(q.w & 0xffff0000u), acc[7]);
    }
    // butterfly reduce-scatter over grp bits, keeping j = grp
    const int g0 = grp & 1, g1 = (grp >> 1) & 1, g2 = grp >> 2;
    float v4[4];
#pragma unroll
    for (int i = 0; i < 4; ++i) {
      const float keep = g0 ? acc[2 * i + 1] : acc[2 * i];
      const float give = g0 ? acc[2 * i] : acc[2 * i + 1];
      v4[i] = keep + __shfl_xor(give, 8);
    }
    float v2[2];
#pragma unroll
    for (int i = 0; i < 2; ++i) {
      const float keep = g1 ? v4[2 * i + 1] : v4[2 * i];
      const float give = g1 ? v4[2 * i] : v4[2 * i + 1];
      v2[i] = keep + __shfl_xor(give, 16);
    }
    const float keep = g2 ? v2[1] : v2[0];
    const float give = g2 ? v2[0] : v2[1];
    const float aval = keep + __shfl_xor(give, 32);
    const float h = fmaxf(aval + bias, 0.f);
    const unsigned idxg = (unsigned)node * 64u + (unsigned)feat;
    const bool keepm = (threefry_draw(idxg) >> 31) == 0u;
    out[idxg] = keepm ? h * 2.0f : 0.0f;
  }
}

extern "C" void kernel_launch(void* const* d_in, const int* in_sizes, int n_in,
                              void* d_out, int out_size, void* d_ws, size_t ws_size,
                              hipStream_t stream) {
  const float* x     = (const float*)d_in[0];
  const int*   erow  = (const int*)d_in[1];
  const int*   ecol  = (const int*)d_in[2];
  const float* eval_ = (const float*)d_in[3];
  const float* W     = (const float*)d_in[4];
  const float* b     = (const float*)d_in[5];
  float* out = (float*)d_out;

  // Workspace layout (bytes), total ~32.1 MB:
  char* ws = (char*)d_ws;
  unsigned short* support_h = (unsigned short*)(ws);             // 12,800,000
  unsigned short* wt        = (unsigned short*)(ws + 12800000);  //     16,384
  int*  cursor  = (int*)(ws + 12816384);                         //    100,096 (1564 x 64B)
  int2* eg      = (int2*)(ws + 12916480);                        // 19,218,432 (1564 x 1536 x 8)

  hipLaunchKernelGGL(gcn_wt, dim3(32), dim3(256), 0, stream, W, wt, cursor);
  hipLaunchKernelGGL(gcn_gemm, dim3((N_NODES + 63) / 64), dim3(256), 0, stream,
                     x, wt, support_h);
  hipLaunchKernelGGL(gcn_bin, dim3(NBATCH), dim3(512), 0, stream,
                     erow, ecol, eval_, cursor, eg);
  hipLaunchKernelGGL(gcn_rowagg, dim3(2 * NBUCK), dim3(512), 0, stream,
                     cursor, eg, support_h, b, out);
}